// Round 1
// baseline (4076.054 us; speedup 1.0000x reference)
//
#include <hip/hip_runtime.h>
#include <math.h>

#define BB 4
#define QQ 75
#define NBQ 300        // BB*QQ
#define CC 640
#define HW 121
#define NW 5
#define KS 5
#define SS 25          // NW*KS
#define MS 605         // KS*HW

// workspace float offsets
#define OFF_SNORM 0        // 100*121   = 12100
#define OFF_QNORM 12100    // 300*121   = 36300
#define OFF_PM    48400    // 1500*121  = 181500
#define OFF_PARG  229900   // 1500*121  (int)
#define OFF_PTV   411400   // 1500*121
#define OFF_LOSS  592900   // 300

// ---------------------------------------------------------------------------
// 1/(||x||+eps) per (col, hw) where x is [ncols][CC][HW]
__global__ void norm_kernel(const float* __restrict__ x, float* __restrict__ invn) {
    const int col = blockIdx.x;
    const int hw  = threadIdx.x;
    if (hw >= HW) return;
    const float* p = x + (size_t)col * (CC * HW) + hw;
    float ss = 0.f;
#pragma unroll 8
    for (int c = 0; c < CC; ++c) { float v = p[(size_t)c * HW]; ss = fmaf(v, v, ss); }
    invn[col * HW + hw] = 1.f / (sqrtf(ss) + 1e-8f);
}

// ---------------------------------------------------------------------------
// Per (bq, n): compute simi rows, emit per-mq: running max, argmax (global j),
// mean of top-3 over ms.
__launch_bounds__(256, 2)
__global__ void simi_kernel(const float* __restrict__ sup, const float* __restrict__ qry,
                            const float* __restrict__ inv_sn, const float* __restrict__ inv_qn,
                            float* __restrict__ pm, int* __restrict__ parg,
                            float* __restrict__ ptv)
{
    const int bq  = blockIdx.x;
    const int n   = blockIdx.y;
    const int b   = bq / QQ;
    const int tid = threadIdx.x;

    const float* qbase = qry + (size_t)bq * (CC * HW);
    const float* sbase = sup + (size_t)(b * SS + n * KS) * (CC * HW);
    const float* isn   = inv_sn + (b * SS + n * KS) * HW;   // contiguous [MS]

    __shared__ __align__(16) float As[64][128];   // 32 KB  As[kc][mq]
    __shared__ __align__(16) float Bs[64][64];    // 16 KB  Bs[kc][jj]
    __shared__ float Ct[32][129];                 // 16.5 KB (half-tile scan buffer)
    __shared__ float inv_st[64];
    __shared__ float inv_q[128];

    if (tid < 128) inv_q[tid] = (tid < HW) ? inv_qn[bq * HW + tid] : 0.f;

    float rmax = -INFINITY; int rarg = 0;
    float t0 = -INFINITY, t1 = -INFINITY, t2 = -INFINITY;

    const int tr4 = (tid >> 3) << 2;   // mq base (0..124)
    const int tc8 = (tid & 7) << 3;    // j  base (0..56)

    for (int ms0 = 0; ms0 < MS; ms0 += 64) {
        const int jw = (MS - ms0 < 64) ? (MS - ms0) : 64;
        if (tid < 64) inv_st[tid] = (ms0 + tid < MS) ? isn[ms0 + tid] : 0.f;

        float acc[4][8];
#pragma unroll
        for (int i = 0; i < 4; ++i)
#pragma unroll
            for (int j = 0; j < 8; ++j) acc[i][j] = 0.f;

        for (int c0 = 0; c0 < CC; c0 += 64) {
            __syncthreads();
            // stage A chunk: [64 c][121 mq] (pad to 128)
#pragma unroll
            for (int it = 0; it < 32; ++it) {
                int idx = tid + it * 256;
                int kc = idx >> 7, mq = idx & 127;
                As[kc][mq] = (mq < HW) ? qbase[(size_t)(c0 + kc) * HW + mq] : 0.f;
            }
            // stage B chunk: [64 c][64 j]
#pragma unroll
            for (int it = 0; it < 16; ++it) {
                int idx = tid + it * 256;
                int kc = idx >> 6, jj = idx & 63;
                int ms = ms0 + jj;
                float v = 0.f;
                if (ms < MS) {
                    int k = ms / HW; int hw = ms - k * HW;
                    v = sbase[((size_t)k * CC + (c0 + kc)) * HW + hw];
                }
                Bs[kc][jj] = v;
            }
            __syncthreads();
#pragma unroll 8
            for (int kc = 0; kc < 64; ++kc) {
                const float4 a  = *(const float4*)(&As[kc][tr4]);
                const float4 b0 = *(const float4*)(&Bs[kc][tc8]);
                const float4 b1 = *(const float4*)(&Bs[kc][tc8 + 4]);
                float av[4] = {a.x, a.y, a.z, a.w};
                float bv[8] = {b0.x, b0.y, b0.z, b0.w, b1.x, b1.y, b1.z, b1.w};
#pragma unroll
                for (int mi = 0; mi < 4; ++mi)
#pragma unroll
                    for (int ji = 0; ji < 8; ++ji)
                        acc[mi][ji] = fmaf(av[mi], bv[ji], acc[mi][ji]);
            }
        }

        // apply norms (cosine = raw_dot * inv_q * inv_s)
        float iq[4];
#pragma unroll
        for (int mi = 0; mi < 4; ++mi) iq[mi] = inv_q[tr4 + mi];
        float is[8];
#pragma unroll
        for (int ji = 0; ji < 8; ++ji) is[ji] = inv_st[tc8 + ji];

        // two 32-wide halves through Ct, scanned by threads 0..120
        for (int half = 0; half < 2; ++half) {
            const int lo = half * 32;
            __syncthreads();
            if (tc8 >= lo && tc8 < lo + 32) {
#pragma unroll
                for (int ji = 0; ji < 8; ++ji) {
                    int jl = tc8 + ji - lo;
#pragma unroll
                    for (int mi = 0; mi < 4; ++mi)
                        Ct[jl][tr4 + mi] = acc[mi][ji] * iq[mi] * is[ji];
                }
            }
            __syncthreads();
            const int cnt = jw - lo > 32 ? 32 : (jw - lo);
            if (tid < HW) {
                for (int jj = 0; jj < cnt; ++jj) {
                    float v = Ct[jj][tid];
                    int jg = n * MS + ms0 + lo + jj;
                    if (v > rmax) { rmax = v; rarg = jg; }   // strict > => first-max (jnp tie rule)
                    if (v > t0)      { t2 = t1; t1 = t0; t0 = v; }
                    else if (v > t1) { t2 = t1; t1 = v; }
                    else if (v > t2) { t2 = v; }
                }
            }
        }
    }

    if (tid < HW) {
        int ob = (bq * NW + n) * HW + tid;
        pm[ob]   = rmax;
        parg[ob] = rarg;
        ptv[ob]  = (t0 + t1 + t2) * (1.f / 3.f);
    }
}

// ---------------------------------------------------------------------------
// Merge 5 per-n partials, mutual-NN mask, logits, per-query CE.
__global__ void merge_kernel(const float* __restrict__ pm, const int* __restrict__ parg,
                             const float* __restrict__ ptv, const int* __restrict__ qy,
                             float* __restrict__ losses)
{
    const int bq  = blockIdx.x;
    const int tid = threadIdx.x;   // 128 threads

    __shared__ float cw[128];
    __shared__ int   ag[128];
    __shared__ float tv[NW][128];
    __shared__ float maskf[128];
    __shared__ float lg[8];

    if (tid < HW) {
        float rmax = -INFINITY; int rarg = 0;
#pragma unroll
        for (int n = 0; n < NW; ++n) {
            float v = pm[(bq * NW + n) * HW + tid];
            if (v > rmax) { rmax = v; rarg = parg[(bq * NW + n) * HW + tid]; } // asc n = asc j
            tv[n][tid] = ptv[(bq * NW + n) * HW + tid];
        }
        cw[tid] = rmax + 1.0f;   // class_wise_max
        ag[tid] = rarg;          // query_nearest (global j)
    }
    __syncthreads();
    if (tid < HW) {
        const float mycw = cw[tid];
        const int   myag = ag[tid];
        float ok = 1.f;
        for (int m2 = 0; m2 < HW; ++m2) {
            if (m2 == tid) continue;
            if (ag[m2] == myag) {
                float c2 = cw[m2];
                if (c2 > mycw || (c2 == mycw && m2 < tid)) ok = 0.f;  // first-max over mq
            }
        }
        maskf[tid] = ok;
    }
    __syncthreads();
    if (tid < NW) {
        float s = 0.f;
        for (int mq = 0; mq < HW; ++mq) s += maskf[mq] * tv[tid][mq];
        lg[tid] = s * 0.5f;   // / TEMPERATURE
    }
    __syncthreads();
    if (tid == 0) {
        float m = lg[0];
#pragma unroll
        for (int n2 = 1; n2 < NW; ++n2) m = fmaxf(m, lg[n2]);
        float se = 0.f;
#pragma unroll
        for (int n2 = 0; n2 < NW; ++n2) se += expf(lg[n2] - m);
        int y = qy[bq];
        losses[bq] = -(lg[y] - m - logf(se));
    }
}

// ---------------------------------------------------------------------------
__global__ void reduce_kernel(const float* __restrict__ losses, float* __restrict__ out) {
    const int tid = threadIdx.x;   // 64 threads
    float s = 0.f;
    for (int i = tid; i < NBQ; i += 64) s += losses[i];
#pragma unroll
    for (int off = 32; off > 0; off >>= 1) s += __shfl_down(s, off);
    if (tid == 0) out[0] = s * (1.f / NBQ);
}

// ---------------------------------------------------------------------------
extern "C" void kernel_launch(void* const* d_in, const int* in_sizes, int n_in,
                              void* d_out, int out_size, void* d_ws, size_t ws_size,
                              hipStream_t stream)
{
    const float* sup = (const float*)d_in[0];   // [4][25][640][121]
    const float* qry = (const float*)d_in[1];   // [4][75][640][121]
    const int*   qy  = (const int*)d_in[3];     // [4][75]
    float* out = (float*)d_out;
    float* ws  = (float*)d_ws;

    float* inv_sn = ws + OFF_SNORM;
    float* inv_qn = ws + OFF_QNORM;
    float* pm     = ws + OFF_PM;
    int*   parg   = (int*)(ws + OFF_PARG);
    float* ptv    = ws + OFF_PTV;
    float* losses = ws + OFF_LOSS;

    hipLaunchKernelGGL(norm_kernel, dim3(BB * SS), dim3(128), 0, stream, sup, inv_sn);
    hipLaunchKernelGGL(norm_kernel, dim3(NBQ),     dim3(128), 0, stream, qry, inv_qn);
    hipLaunchKernelGGL(simi_kernel, dim3(NBQ, NW), dim3(256), 0, stream,
                       sup, qry, inv_sn, inv_qn, pm, parg, ptv);
    hipLaunchKernelGGL(merge_kernel, dim3(NBQ), dim3(128), 0, stream, pm, parg, ptv, qy, losses);
    hipLaunchKernelGGL(reduce_kernel, dim3(1), dim3(64), 0, stream, losses, out);
}

// Round 2
// 649.136 us; speedup vs baseline: 6.2792x; 6.2792x over previous
//
#include <hip/hip_runtime.h>
#include <hip/hip_bf16.h>
#include <math.h>

#define BB 4
#define QQ 75
#define NBQ 300        // BB*QQ
#define CC 640
#define HW 121
#define NW 5
#define KS 5
#define SS 25          // NW*KS
#define MS 605         // KS*HW
#define JT 3025        // NW*MS

typedef __attribute__((ext_vector_type(8))) short short8;
typedef __attribute__((ext_vector_type(4))) float f32x4;

// workspace float offsets
#define OFF_SBF   0
#define SBF_F     (BB*JT*CC/2)            // 3,872,000 floats (bf16 storage)
#define OFF_QBF   (OFF_SBF + SBF_F)
#define QBF_F     (NBQ*HW*CC/2)           // 11,616,000 floats
#define NPM       (NBQ*NW*HW)             // 181,500
#define OFF_PM    (OFF_QBF + QBF_F)
#define OFF_PARG  (OFF_PM + NPM)
#define OFF_PTV   (OFF_PARG + NPM)
#define OFF_LOSS  (OFF_PTV + NPM)

__device__ __forceinline__ short8 zero8() {
    short8 v;
#pragma unroll
    for (int i = 0; i < 8; ++i) v[i] = 0;
    return v;
}

// ---------------------------------------------------------------------------
// Normalize each descriptor (over c), cast to bf16, transpose to [col][hw][c].
// col < 100: support (class-major j layout); else query.
__global__ void prep_kernel(const float* __restrict__ sup, const float* __restrict__ qry,
                            __hip_bfloat16* __restrict__ Sbf, __hip_bfloat16* __restrict__ Qbf)
{
    const int col = blockIdx.x;   // 0..399
    const int t   = threadIdx.x;  // 256
    const float* src;
    __hip_bfloat16* dst;
    if (col < BB * SS) {
        const int b = col / SS, s = col % SS;
        const int n = s / KS, k = s % KS;
        src = sup + (size_t)col * (CC * HW);
        dst = Sbf + ((size_t)b * JT + n * MS + k * HW) * CC;   // rows are hw, ld=CC
    } else {
        const int bq = col - BB * SS;
        src = qry + (size_t)bq * (CC * HW);
        dst = Qbf + (size_t)bq * (HW * CC);
    }

    __shared__ float invn[128];
    __shared__ float T[32][128];

    if (t < 128) {
        float ss = 0.f;
        if (t < HW) {
            const float* p = src + t;
#pragma unroll 8
            for (int c = 0; c < CC; ++c) { float v = p[(size_t)c * HW]; ss = fmaf(v, v, ss); }
        }
        invn[t] = (t < HW) ? 1.f / (sqrtf(ss) + 1e-8f) : 0.f;
    }
    __syncthreads();

    for (int c0 = 0; c0 < CC; c0 += 32) {
        __syncthreads();
        // load & scale tile: 32 c-rows x 121 hw (coalesced on hw)
#pragma unroll
        for (int i = 0; i < 16; ++i) {
            int idx = t + i * 256;
            int cc = idx >> 7, hw = idx & 127;
            if (hw < HW) T[cc][hw] = src[(size_t)(c0 + cc) * HW + hw] * invn[hw];
        }
        __syncthreads();
        // write transposed bf16: thread -> (hw = t>>1, half = t&1 covering 16 c)
        const int hw = t >> 1, half = t & 1;
        if (hw < HW) {
            __hip_bfloat16 hv[16];
#pragma unroll
            for (int i = 0; i < 16; ++i) hv[i] = __float2bfloat16(T[half * 16 + i][hw]);
            int4* op = reinterpret_cast<int4*>(dst + (size_t)hw * CC + c0 + half * 16);
            op[0] = reinterpret_cast<int4*>(hv)[0];
            op[1] = reinterpret_cast<int4*>(hv)[1];
        }
    }
}

// ---------------------------------------------------------------------------
// Per (bq, n): MFMA cosine GEMM [121 x 605], per-mq running max/argmax/top-3.
__launch_bounds__(256, 2)
__global__ void simi_kernel(const __hip_bfloat16* __restrict__ Sbf,
                            const __hip_bfloat16* __restrict__ Qbf,
                            float* __restrict__ pm, int* __restrict__ parg,
                            float* __restrict__ ptv)
{
    const int bq  = blockIdx.x;
    const int n   = blockIdx.y;
    const int b   = bq / QQ;
    const int tid = threadIdx.x;
    const int lane = tid & 63, wid = tid >> 6;
    const int l15 = lane & 15, l4 = lane >> 4;
    const int wr0 = (wid & 1) * 64;    // wave row base
    const int wc0 = (wid >> 1) * 64;   // wave col base (tile-local)

    const unsigned short* qbase = (const unsigned short*)(Qbf + (size_t)bq * (HW * CC));
    const unsigned short* sbase = (const unsigned short*)(Sbf + ((size_t)b * JT + n * MS) * CC);

    __shared__ __align__(16) unsigned short AsBuf[128 * 72];  // [m][k] ld=72, 18432 B
    __shared__ __align__(16) unsigned short BsBuf[128 * 72];  // [j][k] ld=72, 18432 B
    float* Ct = (float*)AsBuf;                                // [32][132] overlay, 16896 B

    float rmax = -INFINITY; int rarg = 0;
    float t0 = -INFINITY, t1 = -INFINITY, t2 = -INFINITY;

    for (int ms0 = 0; ms0 < MS; ms0 += 128) {
        f32x4 acc[4][4];
#pragma unroll
        for (int mi = 0; mi < 4; ++mi)
#pragma unroll
            for (int ni = 0; ni < 4; ++ni)
#pragma unroll
                for (int r = 0; r < 4; ++r) acc[mi][ni][r] = 0.f;

        for (int c0 = 0; c0 < CC; c0 += 64) {
            __syncthreads();
            // stage A[128][64] and B[128][64] (16 B per thread per pass)
#pragma unroll
            for (int p = 0; p < 4; ++p) {
                const int idx = tid + p * 256;
                const int row = idx >> 3, ko = (idx & 7) * 8;
                short8 av = zero8();
                if (row < HW) av = *(const short8*)(qbase + (size_t)row * CC + c0 + ko);
                *(short8*)(AsBuf + row * 72 + ko) = av;
                const int j = ms0 + row;
                short8 bv = zero8();
                if (j < MS) bv = *(const short8*)(sbase + (size_t)j * CC + c0 + ko);
                *(short8*)(BsBuf + row * 72 + ko) = bv;
            }
            __syncthreads();
#pragma unroll
            for (int ks = 0; ks < 2; ++ks) {
                const int k0 = ks * 32 + l4 * 8;
                short8 af[4], bf[4];
#pragma unroll
                for (int mi = 0; mi < 4; ++mi)
                    af[mi] = *(const short8*)(AsBuf + (wr0 + mi * 16 + l15) * 72 + k0);
#pragma unroll
                for (int ni = 0; ni < 4; ++ni)
                    bf[ni] = *(const short8*)(BsBuf + (wc0 + ni * 16 + l15) * 72 + k0);
#pragma unroll
                for (int mi = 0; mi < 4; ++mi)
#pragma unroll
                    for (int ni = 0; ni < 4; ++ni)
                        acc[mi][ni] = __builtin_amdgcn_mfma_f32_16x16x32_bf16(
                            af[mi], bf[ni], acc[mi][ni], 0, 0, 0);
            }
        }

        // scan 4 groups of 32 cols through Ct (ascending j => first-max tie rule)
        for (int g = 0; g < 4; ++g) {
            const int gj0 = ms0 + g * 32;
            int cnt = MS - gj0; if (cnt > 32) cnt = 32;
            __syncthreads();
            if (cnt > 0 && (wid >> 1) == (g >> 1)) {
#pragma unroll
                for (int ni2 = 0; ni2 < 2; ++ni2) {
                    const int nf = (g & 1) * 2 + ni2;
                    const int jl = ni2 * 16 + l15;
#pragma unroll
                    for (int mi = 0; mi < 4; ++mi) {
                        const int m0 = wr0 + mi * 16 + l4 * 4;
                        *(f32x4*)(Ct + jl * 132 + m0) = acc[mi][nf];
                    }
                }
            }
            __syncthreads();
            if (cnt > 0 && tid < HW) {
                for (int jj = 0; jj < cnt; ++jj) {
                    const float v = Ct[jj * 132 + tid];
                    const int jg = n * MS + gj0 + jj;
                    if (v > rmax) { rmax = v; rarg = jg; }   // strict > = first-max
                    if (v > t0)      { t2 = t1; t1 = t0; t0 = v; }
                    else if (v > t1) { t2 = t1; t1 = v; }
                    else if (v > t2) { t2 = v; }
                }
            }
        }
    }

    if (tid < HW) {
        const int ob = (bq * NW + n) * HW + tid;
        pm[ob]   = rmax;
        parg[ob] = rarg;
        ptv[ob]  = (t0 + t1 + t2) * (1.f / 3.f);
    }
}

// ---------------------------------------------------------------------------
// Merge 5 per-n partials, mutual-NN mask, logits, per-query CE.
__global__ void merge_kernel(const float* __restrict__ pm, const int* __restrict__ parg,
                             const float* __restrict__ ptv, const int* __restrict__ qy,
                             float* __restrict__ losses)
{
    const int bq  = blockIdx.x;
    const int tid = threadIdx.x;   // 128 threads

    __shared__ float cw[128];
    __shared__ int   ag[128];
    __shared__ float tv[NW][128];
    __shared__ float maskf[128];
    __shared__ float lg[8];

    if (tid < HW) {
        float rmax = -INFINITY; int rarg = 0;
#pragma unroll
        for (int n = 0; n < NW; ++n) {
            float v = pm[(bq * NW + n) * HW + tid];
            if (v > rmax) { rmax = v; rarg = parg[(bq * NW + n) * HW + tid]; } // asc n = asc j
            tv[n][tid] = ptv[(bq * NW + n) * HW + tid];
        }
        cw[tid] = rmax + 1.0f;   // class_wise_max
        ag[tid] = rarg;          // query_nearest (global j)
    }
    __syncthreads();
    if (tid < HW) {
        const float mycw = cw[tid];
        const int   myag = ag[tid];
        float ok = 1.f;
        for (int m2 = 0; m2 < HW; ++m2) {
            if (m2 == tid) continue;
            if (ag[m2] == myag) {
                float c2 = cw[m2];
                if (c2 > mycw || (c2 == mycw && m2 < tid)) ok = 0.f;  // first-max over mq
            }
        }
        maskf[tid] = ok;
    }
    __syncthreads();
    if (tid < NW) {
        float s = 0.f;
        for (int mq = 0; mq < HW; ++mq) s += maskf[mq] * tv[tid][mq];
        lg[tid] = s * 0.5f;   // / TEMPERATURE
    }
    __syncthreads();
    if (tid == 0) {
        float m = lg[0];
#pragma unroll
        for (int n2 = 1; n2 < NW; ++n2) m = fmaxf(m, lg[n2]);
        float se = 0.f;
#pragma unroll
        for (int n2 = 0; n2 < NW; ++n2) se += expf(lg[n2] - m);
        int y = qy[bq];
        losses[bq] = -(lg[y] - m - logf(se));
    }
}

// ---------------------------------------------------------------------------
__global__ void reduce_kernel(const float* __restrict__ losses, float* __restrict__ out) {
    const int tid = threadIdx.x;   // 64 threads
    float s = 0.f;
    for (int i = tid; i < NBQ; i += 64) s += losses[i];
#pragma unroll
    for (int off = 32; off > 0; off >>= 1) s += __shfl_down(s, off);
    if (tid == 0) out[0] = s * (1.f / NBQ);
}

// ---------------------------------------------------------------------------
extern "C" void kernel_launch(void* const* d_in, const int* in_sizes, int n_in,
                              void* d_out, int out_size, void* d_ws, size_t ws_size,
                              hipStream_t stream)
{
    const float* sup = (const float*)d_in[0];   // [4][25][640][121]
    const float* qry = (const float*)d_in[1];   // [4][75][640][121]
    const int*   qy  = (const int*)d_in[3];     // [4][75]
    float* out = (float*)d_out;
    float* ws  = (float*)d_ws;

    __hip_bfloat16* Sbf = (__hip_bfloat16*)(ws + OFF_SBF);
    __hip_bfloat16* Qbf = (__hip_bfloat16*)(ws + OFF_QBF);
    float* pm     = ws + OFF_PM;
    int*   parg   = (int*)(ws + OFF_PARG);
    float* ptv    = ws + OFF_PTV;
    float* losses = ws + OFF_LOSS;

    hipLaunchKernelGGL(prep_kernel, dim3(BB * SS + NBQ), dim3(256), 0, stream,
                       sup, qry, Sbf, Qbf);
    hipLaunchKernelGGL(simi_kernel, dim3(NBQ, NW), dim3(256), 0, stream,
                       Sbf, Qbf, pm, parg, ptv);
    hipLaunchKernelGGL(merge_kernel, dim3(NBQ), dim3(128), 0, stream, pm, parg, ptv, qy, losses);
    hipLaunchKernelGGL(reduce_kernel, dim3(1), dim3(64), 0, stream, losses, out);
}

// Round 3
// 497.716 us; speedup vs baseline: 8.1895x; 1.3042x over previous
//
#include <hip/hip_runtime.h>
#include <hip/hip_bf16.h>
#include <math.h>

#define BB 4
#define QQ 75
#define NBQ 300        // BB*QQ
#define CC 640
#define HW 121
#define NW 5
#define KS 5
#define SS 25          // NW*KS
#define MS 605         // KS*HW
#define JT 3025        // NW*MS

typedef __attribute__((ext_vector_type(8))) short short8;
typedef __attribute__((ext_vector_type(4))) float f32x4;

// workspace float offsets
#define OFF_SBF   0
#define SBF_F     (BB*JT*CC/2)            // 3,872,000 floats (bf16 storage)
#define OFF_QBF   (OFF_SBF + SBF_F)
#define QBF_F     (NBQ*HW*CC/2)           // 11,616,000 floats
#define NPM       (NBQ*NW*HW)             // 181,500
#define OFF_PM    (OFF_QBF + QBF_F)
#define OFF_PARG  (OFF_PM + NPM)
#define OFF_PTV   (OFF_PARG + NPM)
#define OFF_LOSS  (OFF_PTV + NPM)
// invn (48,400 floats) overlays OFF_PM: consumed by prep before simi writes pm

__device__ __forceinline__ void async16(const void* g, void* l) {
    __builtin_amdgcn_global_load_lds(
        (const __attribute__((address_space(1))) unsigned int*)g,
        (__attribute__((address_space(3))) unsigned int*)l, 16, 0, 0);
}

// ---------------------------------------------------------------------------
// invn per (col, hw); cols 0..99 = support, 100..399 = query
__global__ void norm_kernel(const float* __restrict__ sup, const float* __restrict__ qry,
                            float* __restrict__ invn) {
    const int idx = blockIdx.x * 256 + threadIdx.x;
    if (idx >= (BB * SS + NBQ) * HW) return;
    const int col = idx / HW, hw = idx - col * HW;
    const float* p = ((col < BB * SS) ? sup + (size_t)col * (CC * HW)
                                      : qry + (size_t)(col - BB * SS) * (CC * HW)) + hw;
    float ss = 0.f;
#pragma unroll 8
    for (int c = 0; c < CC; ++c) { float v = p[(size_t)c * HW]; ss = fmaf(v, v, ss); }
    invn[idx] = 1.f / (sqrtf(ss) + 1e-8f);
}

// ---------------------------------------------------------------------------
// Normalize+cast+transpose to [col][hw][c] bf16. 4 c-chunks per col.
__global__ void prep_kernel(const float* __restrict__ sup, const float* __restrict__ qry,
                            const float* __restrict__ invn,
                            __hip_bfloat16* __restrict__ Sbf, __hip_bfloat16* __restrict__ Qbf)
{
    const int bx = blockIdx.x;       // 0..1599
    const int col = bx >> 2, ch = bx & 3;
    const int t = threadIdx.x;       // 256
    const float* src;
    __hip_bfloat16* dst;
    if (col < BB * SS) {
        const int b = col / SS, s = col % SS;
        const int n = s / KS, k = s % KS;
        src = sup + (size_t)col * (CC * HW);
        dst = Sbf + ((size_t)b * JT + n * MS + k * HW) * CC;
    } else {
        const int bq = col - BB * SS;
        src = qry + (size_t)bq * (CC * HW);
        dst = Qbf + (size_t)bq * (HW * CC);
    }

    __shared__ float inv[128];
    __shared__ float T[32][128];
    if (t < 128) inv[t] = (t < HW) ? invn[col * HW + t] : 0.f;
    __syncthreads();

    for (int c0 = ch * 160; c0 < ch * 160 + 160; c0 += 32) {
        __syncthreads();
#pragma unroll
        for (int i = 0; i < 16; ++i) {
            int idx = t + i * 256;
            int cc = idx >> 7, hw = idx & 127;
            if (hw < HW) T[cc][hw] = src[(size_t)(c0 + cc) * HW + hw] * inv[hw];
        }
        __syncthreads();
        const int hw = t >> 1, half = t & 1;
        if (hw < HW) {
            __hip_bfloat16 hv[16];
#pragma unroll
            for (int i = 0; i < 16; ++i) hv[i] = __float2bfloat16(T[half * 16 + i][hw]);
            int4* op = reinterpret_cast<int4*>(dst + (size_t)hw * CC + c0 + half * 16);
            op[0] = reinterpret_cast<int4*>(hv)[0];
            op[1] = reinterpret_cast<int4*>(hv)[1];
        }
    }
}

// ---------------------------------------------------------------------------
// Per (bq, n): MFMA cosine GEMM [121 x 605] with register-resident
// top3/argmax reduction. XOR-swizzled ld=64 LDS tiles + global_load_lds(16B).
__launch_bounds__(256, 2)
__global__ void simi_kernel(const __hip_bfloat16* __restrict__ Sbf,
                            const __hip_bfloat16* __restrict__ Qbf,
                            float* __restrict__ pm, int* __restrict__ parg,
                            float* __restrict__ ptv)
{
    const int bq  = blockIdx.x;
    const int n   = blockIdx.y;
    const int b   = bq / QQ;
    const int tid = threadIdx.x;
    const int lane = tid & 63, wid = tid >> 6;
    const int l15 = lane & 15, l4 = lane >> 4;
    const int wr0 = (wid & 1) * 64;    // wave row base
    const int wc0 = (wid >> 1) * 64;   // wave col base (tile-local)

    const unsigned short* qbase = (const unsigned short*)(Qbf + (size_t)bq * (HW * CC));
    const unsigned short* sbase = (const unsigned short*)(Sbf + ((size_t)b * JT + n * MS) * CC);

    __shared__ __align__(16) unsigned short AsBuf[128 * 64];  // 16 KB, ld=64, xor-swizzled
    __shared__ __align__(16) unsigned short BsBuf[128 * 64];  // 16 KB
    __shared__ float4 mbuf[128];                              // 2 KB cross-wave merge

    // staging lane constants: segment s covers rows s*8..s*8+7; slot = lane&7
    const int srow = lane >> 3;              // row within segment
    const int kb   = (lane & 7) ^ srow;      // swizzled k-block held by this lane
    // A global element offsets per pass p (constant for whole block)
    int aoff[4];
#pragma unroll
    for (int p = 0; p < 4; ++p) {
        int arow = wid * 32 + p * 8 + srow;
        int grow = arow < HW ? arow : HW - 1;
        aoff[p] = grow * CC + kb * 8;
    }

    // running per-thread state: 16 C-rows (mi*4+r), top3 + argmax
    float rt0[16], rt1[16], rt2[16]; int ra[16];
#pragma unroll
    for (int i = 0; i < 16; ++i) { rt0[i] = -INFINITY; rt1[i] = -INFINITY; rt2[i] = -INFINITY; ra[i] = 0; }

    for (int ms0 = 0; ms0 < MS; ms0 += 128) {
        // B global offsets for this ms-tile
        int boff[4];
#pragma unroll
        for (int p = 0; p < 4; ++p) {
            int j = ms0 + wid * 32 + p * 8 + srow;
            int jc = j < MS ? j : MS - 1;
            boff[p] = jc * CC + kb * 8;
        }

        f32x4 acc[4][4];
#pragma unroll
        for (int mi = 0; mi < 4; ++mi)
#pragma unroll
            for (int ni = 0; ni < 4; ++ni)
#pragma unroll
                for (int r = 0; r < 4; ++r) acc[mi][ni][r] = 0.f;

        for (int c0 = 0; c0 < CC; c0 += 64) {
            __syncthreads();
#pragma unroll
            for (int p = 0; p < 4; ++p) {
                const int ldso = (wid * 4 + p) * 1024 + lane * 16;
                async16(qbase + aoff[p] + c0, (char*)AsBuf + ldso);
                async16(sbase + boff[p] + c0, (char*)BsBuf + ldso);
            }
            __syncthreads();
#pragma unroll
            for (int ks = 0; ks < 2; ++ks) {
                const int slot = (ks * 4 + l4) ^ (l15 & 7);
                short8 af[4], bf[4];
#pragma unroll
                for (int mi = 0; mi < 4; ++mi)
                    af[mi] = *(const short8*)(AsBuf + (wr0 + mi * 16 + l15) * 64 + slot * 8);
#pragma unroll
                for (int ni = 0; ni < 4; ++ni)
                    bf[ni] = *(const short8*)(BsBuf + (wc0 + ni * 16 + l15) * 64 + slot * 8);
#pragma unroll
                for (int mi = 0; mi < 4; ++mi)
#pragma unroll
                    for (int ni = 0; ni < 4; ++ni)
                        acc[mi][ni] = __builtin_amdgcn_mfma_f32_16x16x32_bf16(
                            af[mi], bf[ni], acc[mi][ni], 0, 0, 0);
            }
        }

        // in-register epilogue: ascending j (nf asc) keeps first-max tie rule
        int jg[4]; bool jvalid[4];
#pragma unroll
        for (int nf = 0; nf < 4; ++nf) {
            const int jl = ms0 + wc0 + nf * 16 + l15;
            jvalid[nf] = (jl < MS);
            jg[nf] = n * MS + jl;
        }
#pragma unroll
        for (int mi = 0; mi < 4; ++mi)
#pragma unroll
            for (int nf = 0; nf < 4; ++nf)
#pragma unroll
                for (int r = 0; r < 4; ++r) {
                    const int si = mi * 4 + r;
                    float v = jvalid[nf] ? acc[mi][nf][r] : -INFINITY;
                    const bool gt = v > rt0[si];
                    ra[si] = gt ? jg[nf] : ra[si];
                    const float m1 = fminf(rt0[si], v);
                    rt0[si] = fmaxf(rt0[si], v);
                    const float m2 = fminf(rt1[si], m1);
                    rt1[si] = fmaxf(rt1[si], m1);
                    rt2[si] = fmaxf(rt2[si], m2);
                }
    }

    // butterfly merge across the 16 lanes of each col-group (masks 1,2,4,8)
#pragma unroll
    for (int si = 0; si < 16; ++si) {
#pragma unroll
        for (int mask = 1; mask <= 8; mask <<= 1) {
            const float o0 = __shfl_xor(rt0[si], mask);
            const float o1 = __shfl_xor(rt1[si], mask);
            const float o2 = __shfl_xor(rt2[si], mask);
            const int   oa = __shfl_xor(ra[si],  mask);
            const bool take = (o0 > rt0[si]) || (o0 == rt0[si] && oa < ra[si]);
            ra[si] = take ? oa : ra[si];
            // insert o0,o1,o2 (sorted desc) sequentially
            float m1 = fminf(rt0[si], o0); rt0[si] = fmaxf(rt0[si], o0);
            float m2 = fminf(rt1[si], m1); rt1[si] = fmaxf(rt1[si], m1);
            rt2[si] = fmaxf(rt2[si], m2);
            m1 = fminf(rt0[si], o1); rt0[si] = fmaxf(rt0[si], o1);
            m2 = fminf(rt1[si], m1); rt1[si] = fmaxf(rt1[si], m1);
            rt2[si] = fmaxf(rt2[si], m2);
            m1 = fminf(rt0[si], o2); rt0[si] = fmaxf(rt0[si], o2);
            m2 = fminf(rt1[si], m1); rt1[si] = fmaxf(rt1[si], m1);
            rt2[si] = fmaxf(rt2[si], m2);
        }
    }

    // select this lane's slot (si == l15) via unrolled chain
    float s0 = rt0[0], s1 = rt1[0], s2 = rt2[0]; int sa = ra[0];
#pragma unroll
    for (int i = 1; i < 16; ++i) {
        const bool p = (l15 == i);
        s0 = p ? rt0[i] : s0; s1 = p ? rt1[i] : s1; s2 = p ? rt2[i] : s2; sa = p ? ra[i] : sa;
    }
    const int m = wr0 + (l15 >> 2) * 16 + l4 * 4 + (l15 & 3);

    if ((wid >> 1) == 0) {
        float4 v; v.x = s0; v.y = s1; v.z = s2; v.w = __int_as_float(sa);
        mbuf[m] = v;
    }
    __syncthreads();
    if ((wid >> 1) == 1) {
        const float4 o = mbuf[m];
        const int oa = __float_as_int(o.w);
        const bool take = (o.x > s0) || (o.x == s0 && oa < sa);
        sa = take ? oa : sa;
        float m1 = fminf(s0, o.x); s0 = fmaxf(s0, o.x);
        float m2 = fminf(s1, m1);  s1 = fmaxf(s1, m1);
        s2 = fmaxf(s2, m2);
        m1 = fminf(s0, o.y); s0 = fmaxf(s0, o.y);
        m2 = fminf(s1, m1);  s1 = fmaxf(s1, m1);
        s2 = fmaxf(s2, m2);
        m1 = fminf(s0, o.z); s0 = fmaxf(s0, o.z);
        m2 = fminf(s1, m1);  s1 = fmaxf(s1, m1);
        s2 = fmaxf(s2, m2);
        if (m < HW) {
            const int ob = (bq * NW + n) * HW + m;
            pm[ob]   = s0;
            parg[ob] = sa;
            ptv[ob]  = (s0 + s1 + s2) * (1.f / 3.f);
        }
    }
}

// ---------------------------------------------------------------------------
// Merge 5 per-n partials, mutual-NN mask, logits, per-query CE.
__global__ void merge_kernel(const float* __restrict__ pm, const int* __restrict__ parg,
                             const float* __restrict__ ptv, const int* __restrict__ qy,
                             float* __restrict__ losses)
{
    const int bq  = blockIdx.x;
    const int tid = threadIdx.x;   // 128 threads

    __shared__ float cw[128];
    __shared__ int   ag[128];
    __shared__ float tv[NW][128];
    __shared__ float maskf[128];
    __shared__ float lg[8];

    if (tid < HW) {
        float rmax = -INFINITY; int rarg = 0;
#pragma unroll
        for (int n = 0; n < NW; ++n) {
            float v = pm[(bq * NW + n) * HW + tid];
            if (v > rmax) { rmax = v; rarg = parg[(bq * NW + n) * HW + tid]; } // asc n = asc j
            tv[n][tid] = ptv[(bq * NW + n) * HW + tid];
        }
        cw[tid] = rmax + 1.0f;   // class_wise_max
        ag[tid] = rarg;          // query_nearest (global j)
    }
    __syncthreads();
    if (tid < HW) {
        const float mycw = cw[tid];
        const int   myag = ag[tid];
        float ok = 1.f;
        for (int m2 = 0; m2 < HW; ++m2) {
            if (m2 == tid) continue;
            if (ag[m2] == myag) {
                float c2 = cw[m2];
                if (c2 > mycw || (c2 == mycw && m2 < tid)) ok = 0.f;  // first-max over mq
            }
        }
        maskf[tid] = ok;
    }
    __syncthreads();
    if (tid < NW) {
        float s = 0.f;
        for (int mq = 0; mq < HW; ++mq) s += maskf[mq] * tv[tid][mq];
        lg[tid] = s * 0.5f;   // / TEMPERATURE
    }
    __syncthreads();
    if (tid == 0) {
        float m = lg[0];
#pragma unroll
        for (int n2 = 1; n2 < NW; ++n2) m = fmaxf(m, lg[n2]);
        float se = 0.f;
#pragma unroll
        for (int n2 = 0; n2 < NW; ++n2) se += expf(lg[n2] - m);
        int y = qy[bq];
        losses[bq] = -(lg[y] - m - logf(se));
    }
}

// ---------------------------------------------------------------------------
__global__ void reduce_kernel(const float* __restrict__ losses, float* __restrict__ out) {
    const int tid = threadIdx.x;   // 64 threads
    float s = 0.f;
    for (int i = tid; i < NBQ; i += 64) s += losses[i];
#pragma unroll
    for (int off = 32; off > 0; off >>= 1) s += __shfl_down(s, off);
    if (tid == 0) out[0] = s * (1.f / NBQ);
}

// ---------------------------------------------------------------------------
extern "C" void kernel_launch(void* const* d_in, const int* in_sizes, int n_in,
                              void* d_out, int out_size, void* d_ws, size_t ws_size,
                              hipStream_t stream)
{
    const float* sup = (const float*)d_in[0];   // [4][25][640][121]
    const float* qry = (const float*)d_in[1];   // [4][75][640][121]
    const int*   qy  = (const int*)d_in[3];     // [4][75]
    float* out = (float*)d_out;
    float* ws  = (float*)d_ws;

    __hip_bfloat16* Sbf = (__hip_bfloat16*)(ws + OFF_SBF);
    __hip_bfloat16* Qbf = (__hip_bfloat16*)(ws + OFF_QBF);
    float* pm     = ws + OFF_PM;
    int*   parg   = (int*)(ws + OFF_PARG);
    float* ptv    = ws + OFF_PTV;
    float* losses = ws + OFF_LOSS;
    float* invn   = ws + OFF_PM;   // overlay: consumed before pm is written

    hipLaunchKernelGGL(norm_kernel, dim3(190), dim3(256), 0, stream, sup, qry, invn);
    hipLaunchKernelGGL(prep_kernel, dim3((BB * SS + NBQ) * 4), dim3(256), 0, stream,
                       sup, qry, invn, Sbf, Qbf);
    hipLaunchKernelGGL(simi_kernel, dim3(NBQ, NW), dim3(256), 0, stream,
                       Sbf, Qbf, pm, parg, ptv);
    hipLaunchKernelGGL(merge_kernel, dim3(NBQ), dim3(128), 0, stream, pm, parg, ptv, qy, losses);
    hipLaunchKernelGGL(reduce_kernel, dim3(1), dim3(64), 0, stream, losses, out);
}